// Round 8
// baseline (698.672 us; speedup 1.0000x reference)
//
#include <hip/hip_runtime.h>

// VariationalMPS R10: persistent kernel with XCD-LOCAL chains.
// 4 independent sweeps (E-L, E-R, N-L, N-R) each pinned to one XCD (runtime
// XCC_ID grouping). Within a chain: plain stores + sc0 (L1-bypass) loads via
// the shared per-XCD L2; sync = per-chain LLC atomic counter barrier (cheap,
// no cache maintenance). Cross-XCD publication only at 4 points (after prep1,
// prep2, chains, dot) via R7-proven leader buffer_wbl2 barriers. Phase math
// is R9-verbatim (identical FLOP order); only staging/addressing changed.

#define D 128
#define W 8
#define NS 40
#define NPAIR 20
#define HALF2 10
#define MSZ (D * 2 * D)        // 32768
#define HSZ (W * W * 2 * 2)    // 256
#define M2SZ (D * 4 * D)       // 65536  [a][I][c] = a*512+I*128+c
#define H2SZ (W * W * 4 * 4)   // 1024   [w][x][I][J] = w*128+x*16+I*4+J
#define LSZ (D * W * D)        // 131072 [a][w][b] = a*1024+w*128+b
#define NSZ (D * D)            // 16384
#define T2SZ (D * W * D * 4)   // 524288 [p][x][b][J] = p*4096+x*512+b*4+J
#define TNSZ (4 * D * D)       // 65536  [I][p][b] = I*16384+p*128+b

#define OFF_M2 0
#define OFF_MR2 (OFF_M2 + NPAIR * M2SZ)
#define OFF_H2 (OFF_MR2 + HALF2 * M2SZ)
#define OFF_HR2 (OFF_H2 + NPAIR * H2SZ)
#define OFF_LL (OFF_HR2 + HALF2 * H2SZ)
#define OFF_LR (OFF_LL + LSZ)
#define OFF_NL (OFF_LR + LSZ)
#define OFF_NR (OFF_NL + NSZ)
#define OFF_T2L (OFF_NR + NSZ)
#define OFF_T2R (OFF_T2L + T2SZ)
#define OFF_TNL (OFF_T2R + T2SZ)
#define OFF_TNR (OFF_TNL + TNSZ)
#define OFF_PART (OFF_TNR + TNSZ)          // 128 partials, stride 32
#define OFF_PARTN (OFF_PART + 128 * 32)
#define WS_FLOATS (OFF_PARTN + 128 * 32)

#define NBLK 256
#define OFF_BAR WS_FLOATS
#define BAR_CLEAN (32 * NBLK)              // clean[x] = bar[BAR_CLEAN+32x]
#define BAR_CNT (BAR_CLEAN + 32 * 8)       // cnt[x]
#define BAR_LCTR (BAR_CNT + 32 * 8)        // lctr[chain]
#define BAR_INTS (BAR_LCTR + 32 * 4)

#define PR2_TOT (HALF2 * M2SZ + HALF2 * H2SZ)

typedef float f32x4_t __attribute__((ext_vector_type(4)));

__device__ __forceinline__ int ld_rlx(int* p) {
    return __hip_atomic_load(p, __ATOMIC_RELAXED, __HIP_MEMORY_SCOPE_AGENT);
}
__device__ __forceinline__ void st_rlx(int* p, int v) {
    __hip_atomic_store(p, v, __ATOMIC_RELAXED, __HIP_MEMORY_SCOPE_AGENT);
}
__device__ __forceinline__ int fadd_rlx(int* p, int v) {
    return __hip_atomic_fetch_add(p, v, __ATOMIC_RELAXED, __HIP_MEMORY_SCOPE_AGENT);
}

// sc0 loads: bypass the per-CU L1 (which is not coherent with other CUs'
// writes inside a persistent kernel); hit the shared per-XCD L2.
__device__ __forceinline__ float ld_sc0(const float* p) {
    float v;
    asm volatile("global_load_dword %0, %1, off sc0\n\ts_waitcnt vmcnt(0)"
                 : "=&v"(v) : "v"(p) : "memory");
    return v;
}
__device__ __forceinline__ void ld1x4_sc0(const float* p0, const float* p1,
                                          const float* p2, const float* p3,
                                          float& v0, float& v1, float& v2, float& v3) {
    asm volatile(
        "global_load_dword %0, %4, off sc0\n\t"
        "global_load_dword %1, %5, off sc0\n\t"
        "global_load_dword %2, %6, off sc0\n\t"
        "global_load_dword %3, %7, off sc0\n\t"
        "s_waitcnt vmcnt(0)"
        : "=&v"(v0), "=&v"(v1), "=&v"(v2), "=&v"(v3)
        : "v"(p0), "v"(p1), "v"(p2), "v"(p3) : "memory");
}
__device__ __forceinline__ void ld4x2_sc0(const float* p0, const float* p1,
                                          f32x4_t& v0, f32x4_t& v1) {
    asm volatile(
        "global_load_dwordx4 %0, %2, off sc0\n\t"
        "global_load_dwordx4 %1, %3, off sc0\n\t"
        "s_waitcnt vmcnt(0)"
        : "=&v"(v0), "=&v"(v1) : "v"(p0), "v"(p1) : "memory");
}
__device__ __forceinline__ void ld4x4_sc0(const float* p0, const float* p1,
                                          const float* p2, const float* p3,
                                          f32x4_t& v0, f32x4_t& v1,
                                          f32x4_t& v2, f32x4_t& v3) {
    asm volatile(
        "global_load_dwordx4 %0, %4, off sc0\n\t"
        "global_load_dwordx4 %1, %5, off sc0\n\t"
        "global_load_dwordx4 %2, %6, off sc0\n\t"
        "global_load_dwordx4 %3, %7, off sc0\n\t"
        "s_waitcnt vmcnt(0)"
        : "=&v"(v0), "=&v"(v1), "=&v"(v2), "=&v"(v3)
        : "v"(p0), "v"(p1), "v"(p2), "v"(p3) : "memory");
}

__global__ __launch_bounds__(256) void k_bzero(float* ws) {
    int idx = blockIdx.x * 256 + threadIdx.x;
    int* bar = (int*)(ws + OFF_BAR);
    if (idx < BAR_INTS) bar[idx] = 0;
}

// Global barrier: vmcnt drain + arrive slot + all-thread gather of 256 slots;
// optional leader wbl2 publication (R7-proven release fence) + clean-flag poll.
__device__ void gbar(int* bar, int ep, bool wb, int isLead, int myxcd,
                     unsigned presMask) {
    int t = threadIdx.x;
    asm volatile("s_waitcnt vmcnt(0)" ::: "memory");
    __syncthreads();
    if (t == 0) st_rlx(&bar[32 * blockIdx.x], ep);
    while (ld_rlx(&bar[32 * t]) < ep) __builtin_amdgcn_s_sleep(2);
    __syncthreads();
    if (wb) {
        if (isLead && t == 0) {
            __builtin_amdgcn_fence(__ATOMIC_RELEASE, "agent");  // waitcnt+buffer_wbl2
            st_rlx(&bar[BAR_CLEAN + 32 * myxcd], ep);
        }
        if (t < 8 && ((presMask >> t) & 1)) {
            while (ld_rlx(&bar[BAR_CLEAN + 32 * t]) < ep) __builtin_amdgcn_s_sleep(2);
        }
        __syncthreads();
    }
}

// XCD-local barrier: counter at LLC; data visibility within the XCD comes from
// the shared L2 (stores drained by vmcnt(0) before arrival).
__device__ __forceinline__ void lbar(int* lc, int target) {
    asm volatile("s_waitcnt vmcnt(0)" ::: "memory");
    __syncthreads();
    if (threadIdx.x == 0) {
        fadd_rlx(lc, 1);
        while (ld_rlx(lc) < target) __builtin_amdgcn_s_sleep(2);
    }
    __syncthreads();
}

// ---------------- prep1: one pair-GEMM tile (tasks 0..639) or H2 chunk ------
__device__ void prep1_task(int task, const float* Min, const float* Hin,
                           float* ws, float* sm, int t) {
    if (task < 640) {
        float* As = sm;          // [32][34]
        float* Bs = sm + 1088;   // [32][68]
        int m = task >> 5, tile = task & 31;
        int r0 = (tile & 7) * 32, c0 = (tile >> 3) * 64;
        const float* A = Min + (2 * m) * MSZ;
        const float* B = Min + (2 * m + 1) * MSZ;
        float* C = ws + OFF_M2 + m * M2SZ;
        int ty = t >> 4, tx = t & 15;
        float a00 = 0, a01 = 0, a02 = 0, a03 = 0;
        float a10 = 0, a11 = 0, a12 = 0, a13 = 0;
        for (int c = 0; c < 4; ++c) {
            int k0 = c * 32;
            __syncthreads();
            {
                int rr = t >> 3, kq = t & 7;
                int row = r0 + rr;
                const f32x4_t v = *(const f32x4_t*)&A[(row >> 1) * 256 + (row & 1) * 128 + k0 + kq * 4];
                float* dst = &As[kq * 136 + rr];
                dst[0] = v.x; dst[34] = v.y; dst[68] = v.z; dst[102] = v.w;
            }
#pragma unroll
            for (int u = 0; u < 2; ++u) {
                int e = u * 256 + t;
                int kk = e >> 4, cq = e & 15;
                const f32x4_t v = *(const f32x4_t*)&B[(k0 + kk) * 256 + c0 + cq * 4];
                *(f32x4_t*)&Bs[kk * 68 + cq * 4] = v;
            }
            __syncthreads();
#pragma unroll 8
            for (int kk = 0; kk < 32; ++kk) {
                float av0 = As[kk * 34 + 2 * ty], av1 = As[kk * 34 + 2 * ty + 1];
                f32x4_t bv = *(const f32x4_t*)&Bs[kk * 68 + 4 * tx];
                a00 += av0 * bv.x; a01 += av0 * bv.y; a02 += av0 * bv.z; a03 += av0 * bv.w;
                a10 += av1 * bv.x; a11 += av1 * bv.y; a12 += av1 * bv.z; a13 += av1 * bv.w;
            }
        }
        int r = r0 + 2 * ty, cc = c0 + 4 * tx;
        int a = r >> 1, i2 = cc >> 7, cd = cc & 127;
        f32x4_t v0; v0.x = a00; v0.y = a01; v0.z = a02; v0.w = a03;
        f32x4_t v1; v1.x = a10; v1.y = a11; v1.z = a12; v1.w = a13;
        *(f32x4_t*)&C[a * 512 + (0 * 2 + i2) * 128 + cd] = v0;
        *(f32x4_t*)&C[a * 512 + (1 * 2 + i2) * 128 + cd] = v1;
    } else {
        int chunk = task - 640;               // 16 chunks x 1280 elems
        for (int idx = chunk * 1280 + t; idx < (chunk + 1) * 1280; idx += 256) {
            int m = idx >> 10, r = idx & 1023;
            int w = r >> 7, x = (r >> 4) & 7, I = (r >> 2) & 3, J = r & 3;
            int i1 = I >> 1, i2 = I & 1, j1 = J >> 1, j2 = J & 1;
            const float* Ha = Hin + (2 * m) * HSZ;
            const float* Hb = Hin + (2 * m + 1) * HSZ;
            float s = 0.f;
#pragma unroll
            for (int v = 0; v < 8; ++v)
                s += Ha[w * 32 + v * 4 + i1 * 2 + j1] * Hb[v * 32 + x * 4 + i2 * 2 + j2];
            ws[OFF_H2 + idx] = s;
        }
    }
}

// ---------------- energy A task (eb 0..63): R9 body, sc0 L-stage ------------
__device__ void eA_task(int eb, const float* L, const float* m2, const float* h2,
                        float* T2, float* sm, int t) {
    int b0 = (eb & 7) * 16;
    int p0 = (eb >> 3) * 16;
    float* Ls = sm;          // [32a][16b][12w-pad], stride 200 (6400)
    float* ms = sm + 6400;   // [32a][4I][16p] (2048)
    float* hs = sm + 8448;   // [32 wI][32 xJ] (1024)
    __syncthreads();         // protect hs against previous task's fuse reads
#pragma unroll
    for (int u = 0; u < 4; ++u) {
        int e = u * 256 + t;
        int w = e >> 7, I = (e >> 5) & 3, x = (e >> 2) & 7, J = e & 3;
        hs[e] = h2[w * 128 + x * 16 + I * 4 + J];
    }
    int b_l = t & 15, p_l = t >> 4;
    float acc[8][4];
#pragma unroll
    for (int w = 0; w < 8; ++w)
#pragma unroll
        for (int I = 0; I < 4; ++I) acc[w][I] = 0.f;
    for (int c = 0; c < 4; ++c) {
        int a0 = c * 32;
        __syncthreads();
        {   // stage L: 4 float4/thread, sc0 batched
            int e0 = t, e1 = 256 + t, e2 = 512 + t, e3 = 768 + t;
            const float* q0 = &L[(a0 + (e0 >> 5)) * 1024 + ((e0 >> 2) & 7) * 128 + b0 + (e0 & 3) * 4];
            const float* q1 = &L[(a0 + (e1 >> 5)) * 1024 + ((e1 >> 2) & 7) * 128 + b0 + (e1 & 3) * 4];
            const float* q2 = &L[(a0 + (e2 >> 5)) * 1024 + ((e2 >> 2) & 7) * 128 + b0 + (e2 & 3) * 4];
            const float* q3 = &L[(a0 + (e3 >> 5)) * 1024 + ((e3 >> 2) & 7) * 128 + b0 + (e3 & 3) * 4];
            f32x4_t v0, v1, v2, v3;
            ld4x4_sc0(q0, q1, q2, q3, v0, v1, v2, v3);
            float* d0 = &Ls[(e0 >> 5) * 200 + (e0 & 3) * 48 + ((e0 >> 2) & 7)];
            d0[0] = v0.x; d0[12] = v0.y; d0[24] = v0.z; d0[36] = v0.w;
            float* d1 = &Ls[(e1 >> 5) * 200 + (e1 & 3) * 48 + ((e1 >> 2) & 7)];
            d1[0] = v1.x; d1[12] = v1.y; d1[24] = v1.z; d1[36] = v1.w;
            float* d2 = &Ls[(e2 >> 5) * 200 + (e2 & 3) * 48 + ((e2 >> 2) & 7)];
            d2[0] = v2.x; d2[12] = v2.y; d2[24] = v2.z; d2[36] = v2.w;
            float* d3 = &Ls[(e3 >> 5) * 200 + (e3 & 3) * 48 + ((e3 >> 2) & 7)];
            d3[0] = v3.x; d3[12] = v3.y; d3[24] = v3.z; d3[36] = v3.w;
        }
#pragma unroll
        for (int u = 0; u < 2; ++u) {   // stage M2 (immutable): plain
            int s = u * 256 + t;
            int aa = s >> 4, I = (s >> 2) & 3, pq = s & 3;
            const f32x4_t v = *(const f32x4_t*)&m2[(a0 + aa) * 512 + I * 128 + p0 + pq * 4];
            *(f32x4_t*)&ms[aa * 64 + I * 16 + pq * 4] = v;
        }
        __syncthreads();
#pragma unroll 4
        for (int aa = 0; aa < 32; ++aa) {
            f32x4_t l0 = *(const f32x4_t*)&Ls[aa * 200 + b_l * 12];
            f32x4_t l1 = *(const f32x4_t*)&Ls[aa * 200 + b_l * 12 + 4];
            float lw[8] = {l0.x, l0.y, l0.z, l0.w, l1.x, l1.y, l1.z, l1.w};
            float mv[4];
#pragma unroll
            for (int I = 0; I < 4; ++I) mv[I] = ms[aa * 64 + I * 16 + p_l];
#pragma unroll
            for (int w = 0; w < 8; ++w)
#pragma unroll
                for (int I = 0; I < 4; ++I) acc[w][I] += lw[w] * mv[I];
        }
    }
    float o[32];
#pragma unroll
    for (int xJ = 0; xJ < 32; ++xJ) o[xJ] = 0.f;
#pragma unroll
    for (int wI = 0; wI < 32; ++wI) {
        float tv = acc[wI >> 2][wI & 3];
#pragma unroll
        for (int xJ = 0; xJ < 32; ++xJ) o[xJ] += tv * hs[wI * 32 + xJ];
    }
    int b = b0 + b_l, p = p0 + p_l;
#pragma unroll
    for (int x = 0; x < 8; ++x) {
        f32x4_t v; v.x = o[x * 4]; v.y = o[x * 4 + 1]; v.z = o[x * 4 + 2]; v.w = o[x * 4 + 3];
        *(f32x4_t*)&T2[p * 4096 + x * 512 + b * 4] = v;
    }
}

// ---------------- energy B task (eb 0..63): 64-wide k chunks, sc0 T2 --------
__device__ void eB_task(int eb, const float* T2A, const float* m2, float* Lout,
                        float* sm, int t) {
    float* As = sm;           // [64][34] = 2176
    float* Bs = sm + 2176;    // [64][68] = 4352
    int r0 = (eb & 31) * 32;
    int c0 = (eb >> 5) * 64;
    int ty = t >> 4, tx = t & 15;
    float a00 = 0, a01 = 0, a02 = 0, a03 = 0;
    float a10 = 0, a11 = 0, a12 = 0, a13 = 0;
    for (int c = 0; c < 8; ++c) {
        int k0 = c * 64;
        __syncthreads();
        {
            int rr = t >> 3, kq = t & 7;
            const float* p0 = &T2A[(r0 + rr) * 512 + k0 + kq * 4];
            const float* p1 = p0 + 32;
            f32x4_t v0, v1;
            ld4x2_sc0(p0, p1, v0, v1);
            float* d0 = &As[kq * 136 + rr];
            d0[0] = v0.x; d0[34] = v0.y; d0[68] = v0.z; d0[102] = v0.w;
            float* d1 = &As[(kq + 8) * 136 + rr];
            d1[0] = v1.x; d1[34] = v1.y; d1[68] = v1.z; d1[102] = v1.w;
        }
#pragma unroll
        for (int u = 0; u < 4; ++u) {
            int e = u * 256 + t;
            int kk = e >> 4, cq = e & 15;
            int row = k0 + kk;
            const f32x4_t v = *(const f32x4_t*)&m2[(row >> 2) * 512 + (row & 3) * 128 + c0 + cq * 4];
            *(f32x4_t*)&Bs[kk * 68 + cq * 4] = v;
        }
        __syncthreads();
#pragma unroll 8
        for (int kk = 0; kk < 64; ++kk) {
            float av0 = As[kk * 34 + 2 * ty], av1 = As[kk * 34 + 2 * ty + 1];
            f32x4_t bv = *(const f32x4_t*)&Bs[kk * 68 + 4 * tx];
            a00 += av0 * bv.x; a01 += av0 * bv.y; a02 += av0 * bv.z; a03 += av0 * bv.w;
            a10 += av1 * bv.x; a11 += av1 * bv.y; a12 += av1 * bv.z; a13 += av1 * bv.w;
        }
    }
    int r = r0 + 2 * ty, cc = c0 + 4 * tx;
    f32x4_t v0; v0.x = a00; v0.y = a01; v0.z = a02; v0.w = a03;
    f32x4_t v1; v1.x = a10; v1.y = a11; v1.z = a12; v1.w = a13;
    *(f32x4_t*)&Lout[(r >> 3) * 1024 + (r & 7) * 128 + cc] = v0;
    *(f32x4_t*)&Lout[((r + 1) >> 3) * 1024 + ((r + 1) & 7) * 128 + cc] = v1;
}

// ---------------- norm A task (nn 0..31): R9 body, sc0 N-stage --------------
__device__ void nA_task(int nn, const float* N, const float* m2, float* Tn,
                        float* sm, int t) {
    float* As = sm;          // [32][33]
    float* Bs = sm + 1056;   // [32][68]
    int b0 = (nn & 3) * 32;
    int c0 = (nn >> 2) * 64;
    int ty = t >> 4, tx = t & 15;
    float a00 = 0, a01 = 0, a02 = 0, a03 = 0;
    float a10 = 0, a11 = 0, a12 = 0, a13 = 0;
    for (int c = 0; c < 4; ++c) {
        int a0 = c * 32;
        __syncthreads();
        {
            int e0 = t, e1 = 256 + t, e2 = 512 + t, e3 = 768 + t;
            const float* q0 = &N[(a0 + (e0 >> 5)) * 128 + b0 + (e0 & 31)];
            const float* q1 = &N[(a0 + (e1 >> 5)) * 128 + b0 + (e1 & 31)];
            const float* q2 = &N[(a0 + (e2 >> 5)) * 128 + b0 + (e2 & 31)];
            const float* q3 = &N[(a0 + (e3 >> 5)) * 128 + b0 + (e3 & 31)];
            float f0, f1, f2, f3;
            ld1x4_sc0(q0, q1, q2, q3, f0, f1, f2, f3);
            As[(e0 >> 5) * 33 + (e0 & 31)] = f0;
            As[(e1 >> 5) * 33 + (e1 & 31)] = f1;
            As[(e2 >> 5) * 33 + (e2 & 31)] = f2;
            As[(e3 >> 5) * 33 + (e3 & 31)] = f3;
        }
#pragma unroll
        for (int u = 0; u < 2; ++u) {
            int e = u * 256 + t;
            int kk = e >> 4, cq = e & 15;
            const f32x4_t v = *(const f32x4_t*)&m2[(a0 + kk) * 512 + c0 + cq * 4];
            *(f32x4_t*)&Bs[kk * 68 + cq * 4] = v;
        }
        __syncthreads();
#pragma unroll 8
        for (int kk = 0; kk < 32; ++kk) {
            float av0 = As[kk * 33 + 2 * ty], av1 = As[kk * 33 + 2 * ty + 1];
            f32x4_t bv = *(const f32x4_t*)&Bs[kk * 68 + 4 * tx];
            a00 += av0 * bv.x; a01 += av0 * bv.y; a02 += av0 * bv.z; a03 += av0 * bv.w;
            a10 += av1 * bv.x; a11 += av1 * bv.y; a12 += av1 * bv.z; a13 += av1 * bv.w;
        }
    }
    int b_ = b0 + 2 * ty;
    float rowv[2][4] = {{a00, a01, a02, a03}, {a10, a11, a12, a13}};
#pragma unroll
    for (int jj = 0; jj < 4; ++jj) {
        int col = c0 + 4 * tx + jj;
        int I = col >> 7, p = col & 127;
        Tn[I * 16384 + p * 128 + b_] = rowv[0][jj];
        Tn[I * 16384 + p * 128 + b_ + 1] = rowv[1][jj];
    }
}

// ---------------- norm B task (nn 0..7): 64-wide k chunks, sc0 Tn -----------
__device__ void nB_task(int nn, const float* Tn, const float* m2, float* Nout,
                        float* sm, int t) {
    float* As = sm;           // [64][34]
    float* Bs = sm + 2176;    // [64][68]
    int r0 = (nn & 3) * 32;
    int c0 = (nn >> 2) * 64;
    int ty = t >> 4, tx = t & 15;
    float a00 = 0, a01 = 0, a02 = 0, a03 = 0;
    float a10 = 0, a11 = 0, a12 = 0, a13 = 0;
    for (int c = 0; c < 8; ++c) {
        int Ic = c >> 1, bc = (c & 1) * 64;
        __syncthreads();
        {
            int rr = t >> 3, kq = t & 7;
            const float* p0 = &Tn[Ic * 16384 + (r0 + rr) * 128 + bc + kq * 4];
            const float* p1 = p0 + 32;
            f32x4_t v0, v1;
            ld4x2_sc0(p0, p1, v0, v1);
            float* d0 = &As[kq * 136 + rr];
            d0[0] = v0.x; d0[34] = v0.y; d0[68] = v0.z; d0[102] = v0.w;
            float* d1 = &As[(kq + 8) * 136 + rr];
            d1[0] = v1.x; d1[34] = v1.y; d1[68] = v1.z; d1[102] = v1.w;
        }
#pragma unroll
        for (int u = 0; u < 4; ++u) {
            int e = u * 256 + t;
            int kk = e >> 4, cq = e & 15;
            const f32x4_t v = *(const f32x4_t*)&m2[(bc + kk) * 512 + Ic * 128 + c0 + cq * 4];
            *(f32x4_t*)&Bs[kk * 68 + cq * 4] = v;
        }
        __syncthreads();
#pragma unroll 8
        for (int kk = 0; kk < 64; ++kk) {
            float av0 = As[kk * 34 + 2 * ty], av1 = As[kk * 34 + 2 * ty + 1];
            f32x4_t bv = *(const f32x4_t*)&Bs[kk * 68 + 4 * tx];
            a00 += av0 * bv.x; a01 += av0 * bv.y; a02 += av0 * bv.z; a03 += av0 * bv.w;
            a10 += av1 * bv.x; a11 += av1 * bv.y; a12 += av1 * bv.z; a13 += av1 * bv.w;
        }
    }
    int r = r0 + 2 * ty, cc = c0 + 4 * tx;
    f32x4_t v0; v0.x = a00; v0.y = a01; v0.z = a02; v0.w = a03;
    f32x4_t v1; v1.x = a10; v1.y = a11; v1.z = a12; v1.w = a13;
    *(f32x4_t*)&Nout[r * 128 + cc] = v0;
    *(f32x4_t*)&Nout[(r + 1) * 128 + cc] = v1;
}

__global__ __launch_bounds__(256) void k_sweep(const float* __restrict__ Min,
                                               const float* __restrict__ Hin,
                                               float* __restrict__ ws,
                                               float* __restrict__ out) {
    __shared__ __align__(16) float sm[9472];
    __shared__ int shI[12];
    int* bar = (int*)(ws + OFF_BAR);
    const int bid = blockIdx.x;
    const int t = threadIdx.x;

    // ---- grouping: rank within actual XCD ----
    if (t == 0) {
        int x;
        asm volatile("s_getreg_b32 %0, hwreg(HW_REG_XCC_ID)" : "=s"(x));
        x &= 7;
        int r = fadd_rlx(&bar[BAR_CNT + 32 * x], 1);
        shI[0] = x; shI[1] = r;
    }
    __syncthreads();
    const int myxcd = shI[0], rank = shI[1];

    gbar(bar, 1, false, 0, 0, 0);   // all cnt[] adds complete

    if (t == 0) {
        int pres[8]; unsigned pm = 0; int np = 0;
        for (int x = 0; x < 8; ++x) {
            int c = ld_rlx(&bar[BAR_CNT + 32 * x]);
            if (x == myxcd) shI[2] = c;
            if (c > 0) { pres[np++] = x; pm |= 1u << x; }
        }
        shI[3] = (rank == 0);
        shI[4] = (int)pm;
        int nmc = 0;
        for (int c = 0; c < 4; ++c)
            if (pres[c % np] == myxcd) shI[6 + nmc++] = c;
        shI[5] = nmc;
    }
    __syncthreads();
    const int n_g = shI[2], isLead = shI[3];
    const unsigned presMask = (unsigned)shI[4];
    const int nMyChains = shI[5];

    // ---- prep1: pair GEMMs + H2 ----
    for (int task = bid; task < 656; task += NBLK)
        prep1_task(task, Min, Hin, ws, sm, t);
    gbar(bar, 2, true, isLead, myxcd, presMask);

    // ---- prep2: rev transposes ----
    for (int idx = bid * 256 + t; idx < PR2_TOT; idx += NBLK * 256) {
        if (idx < HALF2 * M2SZ) {
            int kr = idx >> 16, r = idx & 65535;
            int a = r >> 9, I = (r >> 7) & 3, p = r & 127;
            ws[OFF_MR2 + idx] = ws[OFF_M2 + (19 - kr) * M2SZ + p * 512 + I * 128 + a];
        } else {
            int e = idx - HALF2 * M2SZ;
            int kr = e >> 10, r = e & 1023;
            int w = r >> 7, x = (r >> 4) & 7, lo = r & 15;
            ws[OFF_HR2 + e] = ws[OFF_H2 + (19 - kr) * H2SZ + x * 128 + w * 16 + lo];
        }
    }
    gbar(bar, 3, true, isLead, myxcd, presMask);

    // ---- XCD-local chains ----
    for (int ci = 0; ci < nMyChains; ++ci) {
        int chain = shI[6 + ci];
        int* lc = &bar[BAR_LCTR + 32 * chain];
        int lep = 0;
        int side = chain & 1;
        if (chain < 2) {
            float* L = ws + (side ? OFF_LR : OFF_LL);
            const float* m2b = ws + (side ? OFF_MR2 : OFF_M2);
            const float* h2b = ws + (side ? OFF_HR2 : OFF_H2);
            float* T2 = ws + (side ? OFF_T2R : OFF_T2L);
            int hot = side ? (W - 1) * D : 0;
            for (int i = rank * 256 + t; i < LSZ; i += n_g * 256)
                L[i] = (i == hot) ? 1.f : 0.f;
            ++lep; lbar(lc, lep * n_g);
            for (int k = 0; k < HALF2; ++k) {
                const float* m2 = m2b + k * M2SZ;
                const float* h2 = h2b + k * H2SZ;
                for (int task = rank; task < 64; task += n_g)
                    eA_task(task, L, m2, h2, T2, sm, t);
                ++lep; lbar(lc, lep * n_g);
                for (int task = rank; task < 64; task += n_g)
                    eB_task(task, T2, m2, L, sm, t);
                ++lep; lbar(lc, lep * n_g);
            }
        } else {
            float* N = ws + (side ? OFF_NR : OFF_NL);
            const float* m2b = ws + (side ? OFF_MR2 : OFF_M2);
            float* Tn = ws + (side ? OFF_TNR : OFF_TNL);
            for (int i = rank * 256 + t; i < NSZ; i += n_g * 256)
                N[i] = (i == 0) ? 1.f : 0.f;
            ++lep; lbar(lc, lep * n_g);
            for (int k = 0; k < HALF2; ++k) {
                const float* m2 = m2b + k * M2SZ;
                for (int task = rank; task < 32; task += n_g)
                    nA_task(task, N, m2, Tn, sm, t);
                ++lep; lbar(lc, lep * n_g);
                for (int task = rank; task < 8; task += n_g)
                    nB_task(task, Tn, m2, N, sm, t);
                ++lep; lbar(lc, lep * n_g);
            }
        }
    }
    gbar(bar, 4, true, isLead, myxcd, presMask);

    // ---- dot partials (blocks 0..127) ----
    if (bid < 128) {
        float* se = sm;
        float* sn = sm + 256;
        const float* LL = ws + OFF_LL;
        const float* LR = ws + OFF_LR;
        float e = 0.f;
#pragma unroll
        for (int u = 0; u < 4; ++u) {
            int i = bid * 1024 + u * 256 + t;
            e += ld_sc0(&LL[i]) * ld_sc0(&LR[i]);
        }
        float n = 0.f;
        if (t < 128) {
            int i = bid * 128 + t;
            n = ld_sc0(&ws[OFF_NL + i]) * ld_sc0(&ws[OFF_NR + i]);
        }
        se[t] = e;
        sn[t] = n;
        __syncthreads();
        for (int s = 128; s > 0; s >>= 1) {
            if (t < s) { se[t] += se[t + s]; sn[t] += sn[t + s]; }
            __syncthreads();
        }
        if (t == 0) {
            ws[OFF_PART + bid * 32] = se[0];
            ws[OFF_PARTN + bid * 32] = sn[0];
        }
    }
    gbar(bar, 5, true, isLead, myxcd, presMask);

    // ---- final reduce + loss ----
    if (bid == 0) {
        float* se = sm;
        float* sn = sm + 128;
        if (t < 128) {
            se[t] = ws[OFF_PART + t * 32];
            sn[t] = ws[OFF_PARTN + t * 32];
        }
        __syncthreads();
        for (int s = 64; s > 0; s >>= 1) {
            if (t < s) { se[t] += se[t + s]; sn[t] += sn[t + s]; }
            __syncthreads();
        }
        if (t == 0) {
            float E = se[0], Nm = sn[0];
            out[0] = E;
            out[1] = Nm;
            out[2] = E / Nm;
            out[3] = fmaxf(Nm - 10000.0f, 0.0f);
        }
    }
}

extern "C" void kernel_launch(void* const* d_in, const int* in_sizes, int n_in,
                              void* d_out, int out_size, void* d_ws, size_t ws_size,
                              hipStream_t stream) {
    const float* Min = (const float*)d_in[0];
    const float* Hin = (const float*)d_in[1];
    float* ws = (float*)d_ws;
    float* out = (float*)d_out;
    (void)in_sizes; (void)n_in; (void)out_size; (void)ws_size;

    k_bzero<<<dim3((BAR_INTS + 255) / 256), dim3(256), 0, stream>>>(ws);
    k_sweep<<<dim3(NBLK), dim3(256), 0, stream>>>(Min, Hin, ws, out);
}

// Round 9
// 385.888 us; speedup vs baseline: 1.8106x; 1.8106x over previous
//
#include <hip/hip_runtime.h>

// VariationalMPS R11: R9 multi-launch skeleton (proven 477us, coherence free at
// dispatch boundaries) with latency-attacked phases:
//  - 512-thread blocks (8 waves/CU vs 4): z=t>>8 splits I-dim (energy A) or
//    k-chunks (energy/norm B) with LDS partial reduction; norm A: z = task.
//  - register-prefetch double buffering in energy A/B chunk loops (next chunk's
//    global loads issued before compute -> L2 latency hidden).
// All contraction formulas verbatim R9; only thread decomposition changed.

#define D 128
#define W 8
#define NS 40
#define NPAIR 20
#define HALF2 10
#define MSZ (D * 2 * D)        // 32768
#define HSZ (W * W * 2 * 2)    // 256
#define M2SZ (D * 4 * D)       // 65536  [a][I][c] = a*512+I*128+c
#define H2SZ (W * W * 4 * 4)   // 1024   [w][x][I][J] = w*128+x*16+I*4+J
#define LSZ (D * W * D)        // 131072 [a][w][b] (= [p][x][q] after B)
#define NSZ (D * D)            // 16384
#define T2SZ (D * W * D * 4)   // 524288 [p][x][b][J] = p*4096+x*512+b*4+J
#define TNSZ (4 * D * D)       // 65536  [I][p][b]

#define OFF_M2 0
#define OFF_MR2 (OFF_M2 + NPAIR * M2SZ)
#define OFF_H2 (OFF_MR2 + HALF2 * M2SZ)
#define OFF_HR2 (OFF_H2 + NPAIR * H2SZ)
#define OFF_LL (OFF_HR2 + HALF2 * H2SZ)
#define OFF_LR (OFF_LL + LSZ)
#define OFF_NL (OFF_LR + LSZ)
#define OFF_NR (OFF_NL + NSZ)
#define OFF_T2L (OFF_NR + NSZ)
#define OFF_T2R (OFF_T2L + T2SZ)
#define OFF_TNL (OFF_T2R + T2SZ)
#define OFF_TNR (OFF_TNL + TNSZ)
#define OFF_PART (OFF_TNR + TNSZ)
#define OFF_PARTN (OFF_PART + 128)

// ---------------- prep1: pair GEMMs M2 (640 blocks) + H2 (block 640) --------
__global__ __launch_bounds__(256) void k_prep1(const float* __restrict__ Min,
                                               const float* __restrict__ Hin,
                                               float* __restrict__ ws) {
    __shared__ float As[32 * 34];
    __shared__ float Bs[32 * 68];
    int bid = blockIdx.x, t = threadIdx.x;
    if (bid < 640) {
        int m = bid >> 5, tile = bid & 31;
        int r0 = (tile & 7) * 32, c0 = (tile >> 3) * 64;
        const float* A = Min + (2 * m) * MSZ;
        const float* B = Min + (2 * m + 1) * MSZ;
        float* C = ws + OFF_M2 + m * M2SZ;
        int ty = t >> 4, tx = t & 15;
        float a00 = 0, a01 = 0, a02 = 0, a03 = 0;
        float a10 = 0, a11 = 0, a12 = 0, a13 = 0;
        for (int c = 0; c < 4; ++c) {
            int k0 = c * 32;
            __syncthreads();
            {
                int rr = t >> 3, kq = t & 7;
                int row = r0 + rr;
                const float4 v = *(const float4*)&A[(row >> 1) * 256 + (row & 1) * 128 + k0 + kq * 4];
                float* dst = &As[kq * 136 + rr];
                dst[0] = v.x; dst[34] = v.y; dst[68] = v.z; dst[102] = v.w;
            }
#pragma unroll
            for (int u = 0; u < 2; ++u) {
                int e = u * 256 + t;
                int kk = e >> 4, cq = e & 15;
                const float4 v = *(const float4*)&B[(k0 + kk) * 256 + c0 + cq * 4];
                *(float4*)&Bs[kk * 68 + cq * 4] = v;
            }
            __syncthreads();
#pragma unroll 8
            for (int kk = 0; kk < 32; ++kk) {
                float2 av = *(float2*)&As[kk * 34 + 2 * ty];
                float4 bv = *(float4*)&Bs[kk * 68 + 4 * tx];
                a00 += av.x * bv.x; a01 += av.x * bv.y; a02 += av.x * bv.z; a03 += av.x * bv.w;
                a10 += av.y * bv.x; a11 += av.y * bv.y; a12 += av.y * bv.z; a13 += av.y * bv.w;
            }
        }
        int r = r0 + 2 * ty, cc = c0 + 4 * tx;
        int a = r >> 1, i2 = cc >> 7, cd = cc & 127;
        float4 v0; v0.x = a00; v0.y = a01; v0.z = a02; v0.w = a03;
        float4 v1; v1.x = a10; v1.y = a11; v1.z = a12; v1.w = a13;
        *(float4*)&C[a * 512 + (0 * 2 + i2) * 128 + cd] = v0;
        *(float4*)&C[a * 512 + (1 * 2 + i2) * 128 + cd] = v1;
    } else {
        for (int idx = t; idx < NPAIR * H2SZ; idx += 256) {
            int m = idx >> 10, r = idx & 1023;
            int w = r >> 7, x = (r >> 4) & 7, I = (r >> 2) & 3, J = r & 3;
            int i1 = I >> 1, i2 = I & 1, j1 = J >> 1, j2 = J & 1;
            const float* Ha = Hin + (2 * m) * HSZ;
            const float* Hb = Hin + (2 * m + 1) * HSZ;
            float s = 0.f;
#pragma unroll
            for (int v = 0; v < 8; ++v)
                s += Ha[w * 32 + v * 4 + i1 * 2 + j1] * Hb[v * 32 + x * 4 + i2 * 2 + j2];
            ws[OFF_H2 + idx] = s;
        }
    }
}

// ---------------- prep2: rev transposes + env init --------------------------
#define PR_MR (HALF2 * M2SZ)
#define PR_HR (PR_MR + HALF2 * H2SZ)
#define PR_TOT (PR_HR + 2 * LSZ + 2 * NSZ)
__global__ __launch_bounds__(256) void k_prep2(float* __restrict__ ws) {
    for (int idx = blockIdx.x * 256 + threadIdx.x; idx < PR_TOT; idx += gridDim.x * 256) {
        if (idx < PR_MR) {
            int kr = idx >> 16, r = idx & 65535;
            int a = r >> 9, I = (r >> 7) & 3, p = r & 127;
            ws[OFF_MR2 + idx] = ws[OFF_M2 + (19 - kr) * M2SZ + p * 512 + I * 128 + a];
        } else if (idx < PR_HR) {
            int e = idx - PR_MR;
            int kr = e >> 10, r = e & 1023;
            int w = r >> 7, x = (r >> 4) & 7, lo = r & 15;
            ws[OFF_HR2 + e] = ws[OFF_H2 + (19 - kr) * H2SZ + x * 128 + w * 16 + lo];
        } else {
            int e = idx - PR_HR;
            int off; float v = 0.f;
            if (e < LSZ)            { off = OFF_LL + e; if (e == 0) v = 1.f; }
            else if (e < 2 * LSZ)   { int r = e - LSZ; off = OFF_LR + r; if (r == (W - 1) * D) v = 1.f; }
            else if (e < 2 * LSZ + NSZ) { int r = e - 2 * LSZ; off = OFF_NL + r; if (r == 0) v = 1.f; }
            else                    { int r = e - 2 * LSZ - NSZ; off = OFF_NR + r; if (r == 0) v = 1.f; }
            ws[off] = v;
        }
    }
}

// ---------------- paired phase A (512 threads) ------------------------------
// Energy blocks 0..127: z splits I (each half: acc[8][2]); fuse partials
// summed via LDS. Norm blocks 128..159: z = task (64 tasks over 32 blocks).
__global__ __launch_bounds__(512) void k_A2(float* __restrict__ ws, int k) {
    __shared__ __align__(16) float sm[9472];
    int bid = blockIdx.x, t = threadIdx.x;
    int z = t >> 8, tl = t & 255;
    if (bid < 128) {
        int side = bid >> 6;
        int eb = bid & 63;
        int b0 = (eb & 7) * 16;
        int p0 = (eb >> 3) * 16;
        const float* Lsrc = ws + (side ? OFF_LR : OFF_LL);
        const float* m2 = ws + (side ? OFF_MR2 : OFF_M2) + k * M2SZ;
        const float* h2 = ws + (side ? OFF_HR2 : OFF_H2) + k * H2SZ;
        float* T2 = ws + (side ? OFF_T2R : OFF_T2L);
        float* Ls = sm;          // [32a][16b][12w-pad] stride 200 (6400)
        float* ms = sm + 6400;   // [32a][4I][16p] (2048)
        float* hs = sm + 8448;   // [32 wI][32 xJ] (1024)
#pragma unroll
        for (int u = 0; u < 2; ++u) {   // stage h2: 1024 over 512 threads
            int e = u * 512 + t;
            int w = e >> 7, I = (e >> 5) & 3, x = (e >> 2) & 7, J = e & 3;
            hs[e] = h2[w * 128 + x * 16 + I * 4 + J];
        }
        int b_l = tl & 15, p_l = tl >> 4;
        float acc[8][2];
#pragma unroll
        for (int w = 0; w < 8; ++w) { acc[w][0] = 0.f; acc[w][1] = 0.f; }
        // prefetch chunk 0 (each thread: 2xfloat4 of L, 1xfloat4 of M2)
        int e0 = t, e1 = 512 + t;
        int la0 = e0 >> 5, lw0 = (e0 >> 2) & 7, lb0 = e0 & 3;
        int la1 = e1 >> 5, lw1 = (e1 >> 2) & 7, lb1 = e1 & 3;
        int maa = t >> 4, mI = (t >> 2) & 3, mpq = t & 3;
        float4 pl0 = *(const float4*)&Lsrc[la0 * 1024 + lw0 * 128 + b0 + lb0 * 4];
        float4 pl1 = *(const float4*)&Lsrc[la1 * 1024 + lw1 * 128 + b0 + lb1 * 4];
        float4 pm = *(const float4*)&m2[maa * 512 + mI * 128 + p0 + mpq * 4];
        for (int c = 0; c < 4; ++c) {
            __syncthreads();
            {
                float* d0 = &Ls[la0 * 200 + lb0 * 48 + lw0];
                d0[0] = pl0.x; d0[12] = pl0.y; d0[24] = pl0.z; d0[36] = pl0.w;
                float* d1 = &Ls[la1 * 200 + lb1 * 48 + lw1];
                d1[0] = pl1.x; d1[12] = pl1.y; d1[24] = pl1.z; d1[36] = pl1.w;
                *(float4*)&ms[maa * 64 + mI * 16 + mpq * 4] = pm;
            }
            if (c < 3) {
                int a0 = (c + 1) * 32;
                pl0 = *(const float4*)&Lsrc[(a0 + la0) * 1024 + lw0 * 128 + b0 + lb0 * 4];
                pl1 = *(const float4*)&Lsrc[(a0 + la1) * 1024 + lw1 * 128 + b0 + lb1 * 4];
                pm = *(const float4*)&m2[(a0 + maa) * 512 + mI * 128 + p0 + mpq * 4];
            }
            __syncthreads();
#pragma unroll 4
            for (int aa = 0; aa < 32; ++aa) {
                float4 l0 = *(float4*)&Ls[aa * 200 + b_l * 12];
                float4 l1 = *(float4*)&Ls[aa * 200 + b_l * 12 + 4];
                float lw[8] = {l0.x, l0.y, l0.z, l0.w, l1.x, l1.y, l1.z, l1.w};
                float mv0 = ms[aa * 64 + (2 * z) * 16 + p_l];
                float mv1 = ms[aa * 64 + (2 * z + 1) * 16 + p_l];
#pragma unroll
                for (int w = 0; w < 8; ++w) {
                    acc[w][0] += lw[w] * mv0;
                    acc[w][1] += lw[w] * mv1;
                }
            }
        }
        // fuse (partial over this z's 16 wI values)
        float o[32];
#pragma unroll
        for (int xJ = 0; xJ < 32; ++xJ) o[xJ] = 0.f;
#pragma unroll
        for (int w = 0; w < 8; ++w)
#pragma unroll
            for (int ii = 0; ii < 2; ++ii) {
                float tv = acc[w][ii];
                int wI = w * 4 + 2 * z + ii;
#pragma unroll
                for (int xJ = 0; xJ < 32; ++xJ) o[xJ] += tv * hs[wI * 32 + xJ];
            }
        __syncthreads();                    // all compute reads of Ls/ms done
        if (z == 1) {                       // red aliases Ls/ms (dead)
#pragma unroll
            for (int j = 0; j < 8; ++j) {
                float4 v; v.x = o[j * 4]; v.y = o[j * 4 + 1];
                v.z = o[j * 4 + 2]; v.w = o[j * 4 + 3];
                *(float4*)&sm[tl * 32 + j * 4] = v;
            }
        }
        __syncthreads();
        if (z == 0) {
#pragma unroll
            for (int j = 0; j < 32; ++j) o[j] += sm[tl * 32 + j];
            int b = b0 + b_l, p = p0 + p_l;
#pragma unroll
            for (int x = 0; x < 8; ++x) {
                float4 v; v.x = o[x * 4]; v.y = o[x * 4 + 1];
                v.z = o[x * 4 + 2]; v.w = o[x * 4 + 3];
                *(float4*)&T2[p * 4096 + x * 512 + b * 4] = v;
            }
        }
    } else {
        int g = (bid - 128) * 2 + z;     // 0..63
        int side = g >> 5;
        int nn = g & 31;
        int b0 = (nn & 3) * 32;
        int c0 = (nn >> 2) * 64;
        const float* Nsrc = ws + (side ? OFF_NR : OFF_NL);
        const float* m2 = ws + (side ? OFF_MR2 : OFF_M2) + k * M2SZ;
        float* Tn = ws + (side ? OFF_TNR : OFF_TNL);
        float* As = sm + z * 3264;       // [32][33]
        float* Bs = sm + z * 3264 + 1056; // [32][68]
        int ty = tl >> 4, tx = tl & 15;
        float a00 = 0, a01 = 0, a02 = 0, a03 = 0;
        float a10 = 0, a11 = 0, a12 = 0, a13 = 0;
        for (int c = 0; c < 4; ++c) {
            int a0 = c * 32;
            __syncthreads();
#pragma unroll
            for (int u = 0; u < 4; ++u) {
                int e = u * 256 + tl;
                int kk = e >> 5, col = e & 31;
                As[kk * 33 + col] = Nsrc[(a0 + kk) * 128 + b0 + col];
            }
#pragma unroll
            for (int u = 0; u < 8; ++u) {
                int e = u * 256 + tl;
                int kk = e >> 6, col = e & 63;
                Bs[kk * 68 + col] = m2[(a0 + kk) * 512 + c0 + col];
            }
            __syncthreads();
#pragma unroll 8
            for (int kk = 0; kk < 32; ++kk) {
                float av0 = As[kk * 33 + 2 * ty], av1 = As[kk * 33 + 2 * ty + 1];
                float4 bv = *(float4*)&Bs[kk * 68 + 4 * tx];
                a00 += av0 * bv.x; a01 += av0 * bv.y; a02 += av0 * bv.z; a03 += av0 * bv.w;
                a10 += av1 * bv.x; a11 += av1 * bv.y; a12 += av1 * bv.z; a13 += av1 * bv.w;
            }
        }
        int b_ = b0 + 2 * ty;
        float rowv[2][4] = {{a00, a01, a02, a03}, {a10, a11, a12, a13}};
#pragma unroll
        for (int jj = 0; jj < 4; ++jj) {
            int col = c0 + 4 * tx + jj;
            int I = col >> 7, p = col & 127;
            Tn[I * 16384 + p * 128 + b_] = rowv[0][jj];
            Tn[I * 16384 + p * 128 + b_ + 1] = rowv[1][jj];
        }
    }
}

// ---------------- paired phase B (512 threads) ------------------------------
// Energy blocks 0..127: z splits the 16 k-chunks (8 each) + LDS reduction;
// register-prefetch double buffer. Norm blocks 128..143: one task per block,
// z splits its 16 chunks (8 each) + LDS reduction.
__global__ __launch_bounds__(512) void k_B2(float* __restrict__ ws, int k) {
    __shared__ __align__(16) float sm[8576];
    int bid = blockIdx.x, t = threadIdx.x;
    int z = t >> 8, tl = t & 255;
    int ty = tl >> 4, tx = tl & 15;
    float a00 = 0, a01 = 0, a02 = 0, a03 = 0;
    float a10 = 0, a11 = 0, a12 = 0, a13 = 0;
    float* As = sm + z * 3264;        // [32][34] = 1088
    float* Bs = sm + z * 3264 + 1088; // [32][68] = 2176
    float* red = sm + 6528;           // 2048
    if (bid < 128) {
        int side = bid >> 6;
        int eb = bid & 63;
        int r0 = (eb & 31) * 32;
        int c0 = (eb >> 5) * 64;
        const float* A = ws + (side ? OFF_T2R : OFF_T2L);
        const float* B = ws + (side ? OFF_MR2 : OFF_M2) + k * M2SZ;
        float* C = ws + (side ? OFF_LR : OFF_LL);
        int rr = tl >> 3, kq = tl & 7;
        int kkb0 = tl >> 4, cq0 = tl & 15;
        int kkb1 = (256 + tl) >> 4, cq1 = tl & 15;
        // prefetch chunk z*8
        int k0 = (z * 8) * 32;
        float4 pa = *(const float4*)&A[(r0 + rr) * 512 + k0 + kq * 4];
        int row0 = k0 + kkb0, row1 = k0 + kkb1;
        float4 pb0 = *(const float4*)&B[(row0 >> 2) * 512 + (row0 & 3) * 128 + c0 + cq0 * 4];
        float4 pb1 = *(const float4*)&B[(row1 >> 2) * 512 + (row1 & 3) * 128 + c0 + cq1 * 4];
        for (int c = 0; c < 8; ++c) {
            __syncthreads();
            {
                float* dst = &As[kq * 136 + rr];
                dst[0] = pa.x; dst[34] = pa.y; dst[68] = pa.z; dst[102] = pa.w;
                *(float4*)&Bs[kkb0 * 68 + cq0 * 4] = pb0;
                *(float4*)&Bs[kkb1 * 68 + cq1 * 4] = pb1;
            }
            if (c < 7) {
                int kn = (z * 8 + c + 1) * 32;
                pa = *(const float4*)&A[(r0 + rr) * 512 + kn + kq * 4];
                int r0n = kn + kkb0, r1n = kn + kkb1;
                pb0 = *(const float4*)&B[(r0n >> 2) * 512 + (r0n & 3) * 128 + c0 + cq0 * 4];
                pb1 = *(const float4*)&B[(r1n >> 2) * 512 + (r1n & 3) * 128 + c0 + cq1 * 4];
            }
            __syncthreads();
#pragma unroll 8
            for (int kk = 0; kk < 32; ++kk) {
                float av0 = As[kk * 34 + 2 * ty], av1 = As[kk * 34 + 2 * ty + 1];
                float4 bv = *(float4*)&Bs[kk * 68 + 4 * tx];
                a00 += av0 * bv.x; a01 += av0 * bv.y; a02 += av0 * bv.z; a03 += av0 * bv.w;
                a10 += av1 * bv.x; a11 += av1 * bv.y; a12 += av1 * bv.z; a13 += av1 * bv.w;
            }
        }
        __syncthreads();
        if (z == 1) {
            float4 v0; v0.x = a00; v0.y = a01; v0.z = a02; v0.w = a03;
            float4 v1; v1.x = a10; v1.y = a11; v1.z = a12; v1.w = a13;
            *(float4*)&red[tl * 8] = v0;
            *(float4*)&red[tl * 8 + 4] = v1;
        }
        __syncthreads();
        if (z == 0) {
            float4 v0 = *(float4*)&red[tl * 8];
            float4 v1 = *(float4*)&red[tl * 8 + 4];
            a00 += v0.x; a01 += v0.y; a02 += v0.z; a03 += v0.w;
            a10 += v1.x; a11 += v1.y; a12 += v1.z; a13 += v1.w;
            int r = r0 + 2 * ty, cc = c0 + 4 * tx;
            float4 w0; w0.x = a00; w0.y = a01; w0.z = a02; w0.w = a03;
            float4 w1; w1.x = a10; w1.y = a11; w1.z = a12; w1.w = a13;
            *(float4*)&C[(r >> 3) * 1024 + (r & 7) * 128 + cc] = w0;
            *(float4*)&C[((r + 1) >> 3) * 1024 + ((r + 1) & 7) * 128 + cc] = w1;
        }
    } else if (bid < 144) {
        int g = bid - 128;               // 16 norm tasks, one per block
        int side = g >> 3;
        int nn = g & 7;
        int r0 = (nn & 3) * 32;
        int c0 = (nn >> 2) * 64;
        const float* A = ws + (side ? OFF_TNR : OFF_TNL);   // [I][p][b]
        const float* B = ws + (side ? OFF_MR2 : OFF_M2) + k * M2SZ;
        float* C = ws + (side ? OFF_NR : OFF_NL);
        for (int c = 0; c < 8; ++c) {
            int cg = z * 8 + c;          // global chunk 0..15
            int Ic = cg >> 2, bc = (cg & 3) * 32;
            __syncthreads();
            {
                int rr = tl >> 3, kq = tl & 7;
                const float4 v = *(const float4*)&A[Ic * 16384 + (r0 + rr) * 128 + bc + kq * 4];
                float* dst = &As[kq * 136 + rr];
                dst[0] = v.x; dst[34] = v.y; dst[68] = v.z; dst[102] = v.w;
            }
#pragma unroll
            for (int u = 0; u < 2; ++u) {
                int e = u * 256 + tl;
                int kk = e >> 4, cq = e & 15;
                const float4 v = *(const float4*)&B[(bc + kk) * 512 + Ic * 128 + c0 + cq * 4];
                *(float4*)&Bs[kk * 68 + cq * 4] = v;
            }
            __syncthreads();
#pragma unroll 8
            for (int kk = 0; kk < 32; ++kk) {
                float av0 = As[kk * 34 + 2 * ty], av1 = As[kk * 34 + 2 * ty + 1];
                float4 bv = *(float4*)&Bs[kk * 68 + 4 * tx];
                a00 += av0 * bv.x; a01 += av0 * bv.y; a02 += av0 * bv.z; a03 += av0 * bv.w;
                a10 += av1 * bv.x; a11 += av1 * bv.y; a12 += av1 * bv.z; a13 += av1 * bv.w;
            }
        }
        __syncthreads();
        if (z == 1) {
            float4 v0; v0.x = a00; v0.y = a01; v0.z = a02; v0.w = a03;
            float4 v1; v1.x = a10; v1.y = a11; v1.z = a12; v1.w = a13;
            *(float4*)&red[tl * 8] = v0;
            *(float4*)&red[tl * 8 + 4] = v1;
        }
        __syncthreads();
        if (z == 0) {
            float4 v0 = *(float4*)&red[tl * 8];
            float4 v1 = *(float4*)&red[tl * 8 + 4];
            a00 += v0.x; a01 += v0.y; a02 += v0.z; a03 += v0.w;
            a10 += v1.x; a11 += v1.y; a12 += v1.z; a13 += v1.w;
            int r = r0 + 2 * ty, cc = c0 + 4 * tx;
            float4 w0; w0.x = a00; w0.y = a01; w0.z = a02; w0.w = a03;
            float4 w1; w1.x = a10; w1.y = a11; w1.z = a12; w1.w = a13;
            *(float4*)&C[r * 128 + cc] = w0;
            *(float4*)&C[(r + 1) * 128 + cc] = w1;
        }
    }
}

// ---------------- dot partials + loss (R9 verbatim) -------------------------
__global__ __launch_bounds__(256) void k_dot(float* __restrict__ ws) {
    __shared__ float se[256], sn[256];
    int bid = blockIdx.x, t = threadIdx.x;
    const float* LL = ws + OFF_LL;
    const float* LR = ws + OFF_LR;
    float e = 0.f;
#pragma unroll
    for (int u = 0; u < 4; ++u) {
        int i = bid * 1024 + u * 256 + t;
        e += LL[i] * LR[i];
    }
    float n = 0.f;
    if (t < 128) {
        int i = bid * 128 + t;
        n = ws[OFF_NL + i] * ws[OFF_NR + i];
    }
    se[t] = e;
    sn[t] = n;
    __syncthreads();
    for (int s = 128; s > 0; s >>= 1) {
        if (t < s) { se[t] += se[t + s]; sn[t] += sn[t + s]; }
        __syncthreads();
    }
    if (t == 0) {
        ws[OFF_PART + bid] = se[0];
        ws[OFF_PARTN + bid] = sn[0];
    }
}

__global__ __launch_bounds__(256) void k_loss(const float* __restrict__ ws,
                                              float* __restrict__ out) {
    __shared__ float se[128], sn[128];
    int t = threadIdx.x;
    if (t < 128) {
        se[t] = ws[OFF_PART + t];
        sn[t] = ws[OFF_PARTN + t];
    }
    __syncthreads();
    for (int s = 64; s > 0; s >>= 1) {
        if (t < s) { se[t] += se[t + s]; sn[t] += sn[t + s]; }
        __syncthreads();
    }
    if (t == 0) {
        float E = se[0], Nm = sn[0];
        out[0] = E;
        out[1] = Nm;
        out[2] = E / Nm;
        out[3] = fmaxf(Nm - 10000.0f, 0.0f);
    }
}

extern "C" void kernel_launch(void* const* d_in, const int* in_sizes, int n_in,
                              void* d_out, int out_size, void* d_ws, size_t ws_size,
                              hipStream_t stream) {
    const float* Min = (const float*)d_in[0];
    const float* Hin = (const float*)d_in[1];
    float* ws = (float*)d_ws;
    float* out = (float*)d_out;
    (void)in_sizes; (void)n_in; (void)out_size; (void)ws_size;

    k_prep1<<<dim3(641), dim3(256), 0, stream>>>(Min, Hin, ws);
    k_prep2<<<dim3(640), dim3(256), 0, stream>>>(ws);
    for (int k = 0; k < HALF2; ++k) {
        k_A2<<<dim3(160), dim3(512), 0, stream>>>(ws, k);
        k_B2<<<dim3(144), dim3(512), 0, stream>>>(ws, k);
    }
    k_dot<<<dim3(128), dim3(256), 0, stream>>>(ws);
    k_loss<<<dim3(1), dim3(256), 0, stream>>>(ws, out);
}